// Round 1
// baseline (413.060 us; speedup 1.0000x reference)
//
#include <hip/hip_runtime.h>
#include <hip/hip_bf16.h>

typedef short v8s __attribute__((ext_vector_type(8)));
typedef float v4f __attribute__((ext_vector_type(4)));

static constexpr int BB = 8, SS = 2048, EE = 512;

enum { EPI_BF16 = 0, EPI_SCALE = 1, EPI_FINAL = 2 };

struct EpiParams {
  float scale;
  const float* bias;            // EPI_FINAL: bias[col]
  const __hip_bfloat16* resid;  // EPI_FINAL: resid[row*resid_ld + col]
  int resid_ld;
};

// LDS union: staging (As 16K | Bs 16K) vs epilogue C-tile
static constexpr int SMEM_BYTES = 34816;

// ---------------- weights f32->bf16 cast (4 tensors, one tiny launch) ----------------
struct CastParams {
  const float* src[4];
  __hip_bfloat16* dst[4];
};

__global__ __launch_bounds__(256) void cast_weights(CastParams cp) {
  const int seg = blockIdx.x >> 7;           // 128 blocks per 512x512 tensor
  const int b = blockIdx.x & 127;
  const float* x = cp.src[seg] + (unsigned long long)b * 2048;
  __hip_bfloat16* y = cp.dst[seg] + (unsigned long long)b * 2048;
  int i = threadIdx.x * 8;
  float4 f0 = ((const float4*)(x + i))[0];
  float4 f1 = ((const float4*)(x + i))[1];
  alignas(16) __hip_bfloat16 h[8];
  h[0] = __float2bfloat16(f0.x); h[1] = __float2bfloat16(f0.y);
  h[2] = __float2bfloat16(f0.z); h[3] = __float2bfloat16(f0.w);
  h[4] = __float2bfloat16(f1.x); h[5] = __float2bfloat16(f1.y);
  h[6] = __float2bfloat16(f1.z); h[7] = __float2bfloat16(f1.w);
  *(uint4*)(y + i) = *(uint4*)h;
}

// ---------------- GEMM staging ----------------
__device__ __forceinline__ void stage_tile64(const __hip_bfloat16* __restrict__ G,
                                             int row0, int ld, int k0,
                                             __hip_bfloat16* lds, int wave, int lane) {
#pragma unroll
  for (int t = 0; t < 4; ++t) {
    const int p = (wave * 4 + t) * 64 + lane;
    const int row = p >> 3;
    const int g = (p & 7) ^ (row & 7);
    const __hip_bfloat16* src = G + (unsigned long long)(row0 + row) * ld + k0 + g * 8;
    __builtin_amdgcn_global_load_lds(
        (const __attribute__((address_space(1))) void*)src,
        (__attribute__((address_space(3))) void*)(lds + (wave * 4 + t) * 512),
        16, 0, 0);
  }
}

__device__ __forceinline__ void stage_tile64_f32(const float* __restrict__ G,
                                                 int row0, int ld, int k0,
                                                 __hip_bfloat16* lds, int tid) {
#pragma unroll
  for (int c = 0; c < 4; ++c) {
    const int p = c * 256 + tid;
    const int row = p >> 3;
    const int g = (p & 7) ^ (row & 7);
    const float* src = G + (unsigned long long)(row0 + row) * ld + k0 + g * 8;
    float4 f0 = ((const float4*)src)[0];
    float4 f1 = ((const float4*)src)[1];
    alignas(16) __hip_bfloat16 h[8];
    h[0] = __float2bfloat16(f0.x); h[1] = __float2bfloat16(f0.y);
    h[2] = __float2bfloat16(f0.z); h[3] = __float2bfloat16(f0.w);
    h[4] = __float2bfloat16(f1.x); h[5] = __float2bfloat16(f1.y);
    h[6] = __float2bfloat16(f1.z); h[7] = __float2bfloat16(f1.w);
    *(uint4*)&lds[p * 8] = *(uint4*)h;
  }
}

// C = A @ B^T. 128x128 tile, BK=64, 256 threads = 4 waves (2x2).
template <int EPI, bool AF32, bool BF32>
__device__ __forceinline__ void gemm_body(const void* Agv, const void* Bgv,
                                          void* Cg, int K, int lda, int ldb, int ldc,
                                          int m0, int n0, const EpiParams& ep,
                                          unsigned char* smem) {
  __hip_bfloat16* As = (__hip_bfloat16*)smem;
  __hip_bfloat16* Bs = As + 128 * 64;

  const int tid = threadIdx.x;
  const int lane = tid & 63;
  const int wave = tid >> 6;
  const int wr = wave >> 1;
  const int wc = wave & 1;

  v4f acc[4][4];
  const v4f vzero = {0.f, 0.f, 0.f, 0.f};
#pragma unroll
  for (int i = 0; i < 4; ++i)
#pragma unroll
    for (int j = 0; j < 4; ++j) acc[i][j] = vzero;

  const int fr = lane & 15;
  const int fq = lane >> 4;

  for (int k0 = 0; k0 < K; k0 += 64) {
    __syncthreads();
    if constexpr (AF32)
      stage_tile64_f32((const float*)Agv, m0, lda, k0, As, tid);
    else
      stage_tile64((const __hip_bfloat16*)Agv, m0, lda, k0, As, wave, lane);
    if constexpr (BF32)
      stage_tile64_f32((const float*)Bgv, n0, ldb, k0, Bs, tid);
    else
      stage_tile64((const __hip_bfloat16*)Bgv, n0, ldb, k0, Bs, wave, lane);
    __syncthreads();

#pragma unroll
    for (int ks = 0; ks < 2; ++ks) {
      const int gq = ks * 4 + fq;
      v8s a[4], b[4];
#pragma unroll
      for (int i = 0; i < 4; ++i) {
        const int r = wr * 64 + i * 16 + fr;
        a[i] = *(const v8s*)&As[r * 64 + ((gq ^ (r & 7)) * 8)];
      }
#pragma unroll
      for (int j = 0; j < 4; ++j) {
        const int r = wc * 64 + j * 16 + fr;
        b[j] = *(const v8s*)&Bs[r * 64 + ((gq ^ (r & 7)) * 8)];
      }
#pragma unroll
      for (int i = 0; i < 4; ++i)
#pragma unroll
        for (int j = 0; j < 4; ++j)
          acc[i][j] = __builtin_amdgcn_mfma_f32_16x16x32_bf16(a[i], b[j], acc[i][j], 0, 0, 0);
    }
  }

  // C/D frag layout: col = lane&15, row = (lane>>4)*4 + reg
  const int cf = lane & 15;
  const int rq = (lane >> 4) * 4;

  __syncthreads();

  if constexpr (EPI != EPI_FINAL) {
    __hip_bfloat16* Ct = (__hip_bfloat16*)smem;
    const int ST = 136;
#pragma unroll
    for (int i = 0; i < 4; ++i) {
      const int rl = wr * 64 + i * 16 + rq;
#pragma unroll
      for (int j = 0; j < 4; ++j) {
        const int col = wc * 64 + j * 16 + cf;
#pragma unroll
        for (int r = 0; r < 4; ++r) {
          float v = acc[i][j][r];
          if constexpr (EPI == EPI_SCALE) v *= ep.scale;
          Ct[(rl + r) * ST + col] = __float2bfloat16(v);
        }
      }
    }
    __syncthreads();
    __hip_bfloat16* C = (__hip_bfloat16*)Cg;
#pragma unroll
    for (int c = 0; c < 8; ++c) {
      const int idx = c * 256 + tid;
      const int row = idx >> 4;
      const int colc = (idx & 15) * 8;
      *(v8s*)&C[(unsigned long long)(m0 + row) * ldc + n0 + colc] =
          *(const v8s*)&Ct[row * ST + colc];
    }
  } else {
    float* Cf = (float*)smem;
    const int ST = 132;
    float* C = (float*)Cg;
#pragma unroll
    for (int h = 0; h < 2; ++h) {
      if (wr == h) {
#pragma unroll
        for (int i = 0; i < 4; ++i) {
          const int rl = i * 16 + rq;
#pragma unroll
          for (int j = 0; j < 4; ++j) {
            const int col = wc * 64 + j * 16 + cf;
#pragma unroll
            for (int r = 0; r < 4; ++r) Cf[(rl + r) * ST + col] = acc[i][j][r];
          }
        }
      }
      __syncthreads();
#pragma unroll
      for (int c = 0; c < 8; ++c) {
        const int idx = c * 256 + tid;
        const int row = idx >> 5;
        const int colc = (idx & 31) * 4;
        const int grow = m0 + h * 64 + row;
        const int gcol = n0 + colc;
        float4 v = *(const float4*)&Cf[row * ST + colc];
        float4 b4 = *(const float4*)&ep.bias[gcol];
        ushort4 r4 = *(const ushort4*)&ep.resid[(unsigned long long)grow * ep.resid_ld + gcol];
        v.x += b4.x + __bfloat162float(*(__hip_bfloat16*)&r4.x);
        v.y += b4.y + __bfloat162float(*(__hip_bfloat16*)&r4.y);
        v.z += b4.z + __bfloat162float(*(__hip_bfloat16*)&r4.z);
        v.w += b4.w + __bfloat162float(*(__hip_bfloat16*)&r4.w);
        *(float4*)&C[(unsigned long long)grow * ldc + gcol] = v;
      }
      if (h == 0) __syncthreads();
    }
  }
}

template <int EPI>
__global__ __launch_bounds__(256, 3) void gemm_bt(
    const __hip_bfloat16* __restrict__ Ag, const __hip_bfloat16* __restrict__ Bg,
    void* __restrict__ Cg, int K, int lda, int ldb, int ldc,
    unsigned long long sAz, unsigned long long sBz, unsigned long long sCz, EpiParams ep) {
  __shared__ __align__(16) unsigned char smem[SMEM_BYTES];
  const unsigned long long z = blockIdx.z;
  void* Cz;
  if constexpr (EPI == EPI_FINAL) Cz = (void*)((float*)Cg + z * sCz);
  else Cz = (void*)((__hip_bfloat16*)Cg + z * sCz);
  gemm_body<EPI, false, false>(Ag + z * sAz, Bg + z * sBz, Cz, K, lda, ldb, ldc,
                               blockIdx.y * 128, blockIdx.x * 128, ep, smem);
}

// q/k/v projections, one launch, cast fused into staging. grid = (128, 4, 3).
__global__ __launch_bounds__(256, 3) void gemm_qkv(
    const float* __restrict__ Q, const float* __restrict__ K,
    const __hip_bfloat16* __restrict__ Wq, const __hip_bfloat16* __restrict__ Wk,
    const __hip_bfloat16* __restrict__ Wv,
    __hip_bfloat16* __restrict__ qb, __hip_bfloat16* __restrict__ kb,
    __hip_bfloat16* __restrict__ vT) {
  __shared__ __align__(16) unsigned char smem[SMEM_BYTES];
  const int z = blockIdx.z;
  EpiParams ep{};
  if (z == 2) {
    gemm_body<EPI_BF16, false, true>(Wv, K, vT, EE, EE, EE, BB * SS,
                                     blockIdx.y * 128, blockIdx.x * 128, ep, smem);
  } else {
    const float* A = (z == 0) ? Q : K;
    const __hip_bfloat16* B = (z == 0) ? Wq : Wk;
    __hip_bfloat16* C = (z == 0) ? qb : kb;
    gemm_body<EPI_BF16, true, false>(A, B, C, EE, EE, EE, EE,
                                     blockIdx.x * 128, blockIdx.y * 128, ep, smem);
  }
}

// ---------------- fused flash attention: scores + mask + softmax + PV ----------------
// One block = (batch b, 64 q-rows). 8 waves / 512 threads, 1 block/CU, grid 256.
// Q fragments in registers; K tiles (64x512) double-buffered in LDS (XOR-swizzled,
// staged via global_load_lds); V fragments register-direct from vT (per-wave disjoint
// 64-wide E slice); P through small double-buffered swizzled LDS tile.
// LDS: Ks 2*64KB + Ps 2*8KB + state 1.75KB = 149248 B -> dynamic shared.
static constexpr int FLASH_LDS = 149248;

__device__ __forceinline__ void stage_K64(const __hip_bfloat16* __restrict__ Kb, int kv0,
                                          __hip_bfloat16* lds, int tid) {
  const int wv = tid >> 6;
#pragma unroll
  for (int c = 0; c < 8; ++c) {
    const int p = c * 512 + tid;           // granule index (16B each), 4096 total
    const int chunk = p >> 9;              // 8 chunks of 64 k-cols
    const int row = (p >> 3) & 63;
    const int g = (p & 7) ^ (row & 7);     // XOR swizzle within chunk
    const __hip_bfloat16* src = Kb + (unsigned long long)(kv0 + row) * 512ull + chunk * 64 + g * 8;
    __builtin_amdgcn_global_load_lds(
        (const __attribute__((address_space(1))) void*)src,
        (__attribute__((address_space(3))) void*)(lds + (c * 512 + wv * 64) * 8),
        16, 0, 0);
  }
}

__global__ __launch_bounds__(512, 2) void flash_attn(
    const __hip_bfloat16* __restrict__ qb, const __hip_bfloat16* __restrict__ kb,
    const __hip_bfloat16* __restrict__ vT, const unsigned char* __restrict__ mask,
    __hip_bfloat16* __restrict__ ob) {
  extern __shared__ __align__(16) char fsm[];
  __hip_bfloat16* Ks0 = (__hip_bfloat16*)fsm;        // [2][8 chunks][64 rows][8 gran]
  __hip_bfloat16* Ps0 = Ks0 + 2 * 32768;             // [2][64][64] swizzled
  float* m_s   = (float*)(fsm + 147456);             // [64] running max
  float* l_s   = m_s + 64;                           // [64] running denom
  float* fac_s = l_s + 64;                           // [64] per-iter rescale
  float* pmax  = fac_s + 64;                         // [2][64] tile-max partials
  float* psum  = pmax + 128;                         // [2][64] tile-sum partials

  const int tid = threadIdx.x;
  const int lane = tid & 63;
  const int w = tid >> 6;          // wave 0..7
  const int fr = lane & 15;
  const int fq = lane >> 4;        // 0..3
  const int wq = w & 3;            // QK q-row group (16 rows each)
  const int wk = w >> 2;           // QK kv-col group (32 cols each)
  const int b = blockIdx.x & 7;    // batch -> XCD-aligned
  const int q0 = (blockIdx.x >> 3) * 64;
  const unsigned long long bS = (unsigned long long)b * 2048ull;
  const float SC = 0.044194173824159216f;  // 512^-0.5

  // Q fragments in registers: rows q0 + wq*16 + fr, full E=512
  v8s qf[16];
  {
    const __hip_bfloat16* qrow = qb + (bS + q0 + wq * 16 + fr) * 512ull;
#pragma unroll
    for (int kk = 0; kk < 16; ++kk) qf[kk] = *(const v8s*)&qrow[kk * 32 + fq * 8];
  }

  v4f acc[4][4];
  const v4f vz = {0.f, 0.f, 0.f, 0.f};
#pragma unroll
  for (int i = 0; i < 4; ++i)
#pragma unroll
    for (int j = 0; j < 4; ++j) acc[i][j] = vz;

  if (tid < 64) { m_s[tid] = -1e30f; l_s[tid] = 0.f; }

  const __hip_bfloat16* Kb = kb + bS * 512ull;
  stage_K64(Kb, 0, Ks0, tid);
  __syncthreads();

  for (int t = 0; t < 32; ++t) {
    __hip_bfloat16* KsT = Ks0 + (t & 1) * 32768;
    __hip_bfloat16* PsT = Ps0 + (t & 1) * 4096;
    if (t < 31) stage_K64(Kb, (t + 1) * 64, Ks0 + ((t + 1) & 1) * 32768, tid);

    const int kv0 = t * 64;

    // mask prefetch (used after QK^T; latency hides under MFMA)
    unsigned char mk[2][4];
#pragma unroll
    for (int j = 0; j < 2; ++j)
#pragma unroll
      for (int r = 0; r < 4; ++r)
        mk[j][r] = mask[(bS + q0 + wq * 16 + fq * 4 + r) * 2048ull + kv0 + wk * 32 + j * 16 + fr];

    // QK^T: S[64 q][64 kv], per wave 16x32 slice
    v4f sa[2] = {vz, vz};
    __builtin_amdgcn_s_setprio(1);
#pragma unroll
    for (int kk = 0; kk < 16; ++kk) {
#pragma unroll
      for (int j = 0; j < 2; ++j) {
        const int rr = wk * 32 + j * 16 + fr;
        v8s kf = *(const v8s*)&KsT[(kk >> 1) * 4096 + rr * 64 + ((((kk & 1) * 4 + fq) ^ (rr & 7)) * 8)];
        sa[j] = __builtin_amdgcn_mfma_f32_16x16x32_bf16(qf[kk], kf, sa[j], 0, 0, 0);
      }
    }
    __builtin_amdgcn_s_setprio(0);

    // scale + mask, per-row tile max (16-lane butterfly)
    float sv[2][4];
    float rmx[4] = {-3e38f, -3e38f, -3e38f, -3e38f};
#pragma unroll
    for (int j = 0; j < 2; ++j)
#pragma unroll
      for (int r = 0; r < 4; ++r) {
        const float x = mk[j][r] ? -1e9f : sa[j][r] * SC;
        sv[j][r] = x;
        rmx[r] = fmaxf(rmx[r], x);
      }
#pragma unroll
    for (int off = 1; off <= 8; off <<= 1)
#pragma unroll
      for (int r = 0; r < 4; ++r) rmx[r] = fmaxf(rmx[r], __shfl_xor(rmx[r], off));
    if (fr == 0)
      *(float4*)&pmax[wk * 64 + wq * 16 + fq * 4] = make_float4(rmx[0], rmx[1], rmx[2], rmx[3]);
    __syncthreads();  // A: pmax ready

    if (tid < 64) {
      const float mo = m_s[tid];
      const float mn = fmaxf(mo, fmaxf(pmax[tid], pmax[64 + tid]));
      m_s[tid] = mn;
      fac_s[tid] = __expf(mo - mn);   // first iter: exp(-1e30-mn) = 0
    }
    __syncthreads();  // B: m_new/fac ready

    // P = exp(S - m_new); write swizzled Ps; row-sum partials; rescale O-acc
    float4 mn4 = *(const float4*)&m_s[wq * 16 + fq * 4];
    const float mnr[4] = {mn4.x, mn4.y, mn4.z, mn4.w};
    float rsm[4] = {0.f, 0.f, 0.f, 0.f};
#pragma unroll
    for (int j = 0; j < 2; ++j) {
      const int col = wk * 32 + j * 16 + fr;
      const int cg = col >> 3, cl = col & 7;
#pragma unroll
      for (int r = 0; r < 4; ++r) {
        const float p = __expf(sv[j][r] - mnr[r]);  // fully-masked row: exp(0)=1 -> uniform (matches ref)
        rsm[r] += p;
        const int row = wq * 16 + fq * 4 + r;
        PsT[row * 64 + ((cg ^ (row & 7)) * 8) + cl] = __float2bfloat16(p);
      }
    }
#pragma unroll
    for (int off = 1; off <= 8; off <<= 1)
#pragma unroll
      for (int r = 0; r < 4; ++r) rsm[r] += __shfl_xor(rsm[r], off);
    if (fr == 0)
      *(float4*)&psum[wk * 64 + wq * 16 + fq * 4] = make_float4(rsm[0], rsm[1], rsm[2], rsm[3]);
#pragma unroll
    for (int i = 0; i < 4; ++i) {
      const float4 f4 = *(const float4*)&fac_s[i * 16 + fq * 4];
      const float fv[4] = {f4.x, f4.y, f4.z, f4.w};
#pragma unroll
      for (int j = 0; j < 4; ++j)
#pragma unroll
        for (int r = 0; r < 4; ++r) acc[i][j][r] *= fv[r];
    }
    __syncthreads();  // C: Ps + psum ready; K-stage drained

    if (tid < 64) l_s[tid] = l_s[tid] * fac_s[tid] + psum[tid] + psum[64 + tid];

    // PV: out[64 q][512 e] += P @ V ; per wave 64x64 (e-cols w*64..)
    __builtin_amdgcn_s_setprio(1);
#pragma unroll
    for (int ks = 0; ks < 2; ++ks) {
      v8s pa[4], vb[4];
#pragma unroll
      for (int i = 0; i < 4; ++i) {
        const int row = i * 16 + fr;
        pa[i] = *(const v8s*)&PsT[row * 64 + (((ks * 4 + fq) ^ (row & 7)) * 8)];
      }
#pragma unroll
      for (int j = 0; j < 4; ++j)
        vb[j] = *(const v8s*)&vT[(unsigned long long)(w * 64 + j * 16 + fr) * 16384ull +
                                 bS + kv0 + ks * 32 + fq * 8];
#pragma unroll
      for (int i = 0; i < 4; ++i)
#pragma unroll
        for (int j = 0; j < 4; ++j)
          acc[i][j] = __builtin_amdgcn_mfma_f32_16x16x32_bf16(pa[i], vb[j], acc[i][j], 0, 0, 0);
    }
    __builtin_amdgcn_s_setprio(0);
  }

  __syncthreads();  // l_s final
#pragma unroll
  for (int i = 0; i < 4; ++i) {
    const float4 l4 = *(const float4*)&l_s[i * 16 + fq * 4];
    const float inv[4] = {1.f / l4.x, 1.f / l4.y, 1.f / l4.z, 1.f / l4.w};
#pragma unroll
    for (int r = 0; r < 4; ++r) {
      __hip_bfloat16* orow = ob + (bS + q0 + i * 16 + fq * 4 + r) * 512ull + w * 64 + fr;
#pragma unroll
      for (int j = 0; j < 4; ++j)
        orow[j * 16] = __float2bfloat16(acc[i][j][r] * inv[r]);
    }
  }
}

extern "C" void kernel_launch(void* const* d_in, const int* in_sizes, int n_in,
                              void* d_out, int out_size, void* d_ws, size_t ws_size,
                              hipStream_t stream) {
  const float* Q = (const float*)d_in[0];
  const float* K = (const float*)d_in[1];
  const unsigned char* mask = (const unsigned char*)d_in[2];
  const float* Wq = (const float*)d_in[3];
  const float* Wk = (const float*)d_in[4];
  const float* Wv = (const float*)d_in[5];
  const float* Wp = (const float*)d_in[6];
  const float* bp = (const float*)d_in[7];
  float* out = (float*)d_out;

  // Workspace:
  //   [0,16)   qb [B*S,E]
  //   [16,32)  kb [B*S,E]   (live through flash -- NOT aliased anymore)
  //   [32,48)  vT [E,B*S]
  //   [48,52)  Wqb,Wkb,Wvb,Wpb
  //   [64,80)  ob [B*S,E]
  char* ws = (char*)d_ws;
  const unsigned long long MB = 1024ull * 1024ull;
  __hip_bfloat16* qb = (__hip_bfloat16*)(ws + 0 * MB);
  __hip_bfloat16* kb = (__hip_bfloat16*)(ws + 16 * MB);
  __hip_bfloat16* vT = (__hip_bfloat16*)(ws + 32 * MB);
  __hip_bfloat16* Wqb = (__hip_bfloat16*)(ws + 48 * MB);
  __hip_bfloat16* Wkb = Wqb + 512 * 512;
  __hip_bfloat16* Wvb = Wkb + 512 * 512;
  __hip_bfloat16* Wpb = Wvb + 512 * 512;
  __hip_bfloat16* ob = (__hip_bfloat16*)(ws + 64 * MB);

  dim3 blk(256, 1, 1);

  // 1) weights cast
  CastParams cp;
  cp.src[0] = Wq; cp.dst[0] = Wqb;
  cp.src[1] = Wk; cp.dst[1] = Wkb;
  cp.src[2] = Wv; cp.dst[2] = Wvb;
  cp.src[3] = Wp; cp.dst[3] = Wpb;
  cast_weights<<<dim3(512, 1, 1), blk, 0, stream>>>(cp);

  // 2) q/k/v projections with fused input cast
  gemm_qkv<<<dim3((BB * SS) / 128, EE / 128, 3), blk, 0, stream>>>(
      Q, K, Wqb, Wkb, Wvb, qb, kb, vT);

  // 3) fused flash attention (scores + mask + softmax + PV), 149 KB LDS
  static bool attr_done = false;
  if (!attr_done) {
    hipFuncSetAttribute((const void*)flash_attn,
                        hipFuncAttributeMaxDynamicSharedMemorySize, FLASH_LDS);
    attr_done = true;
  }
  flash_attn<<<dim3(256, 1, 1), dim3(512, 1, 1), FLASH_LDS, stream>>>(
      qb, kb, vT, mask, ob);

  // 4) out = q + (ob @ Wp^T + bp)  f32
  EpiParams epf{};
  epf.bias = bp;
  epf.resid = qb;
  epf.resid_ld = EE;
  gemm_bt<EPI_FINAL><<<dim3(EE / 128, (BB * SS) / 128, 1), blk, 0, stream>>>(
      ob, Wpb, out, EE, EE, EE, EE, 0ull, 0ull, 0ull, epf);
}